// Round 14
// baseline (68.374 us; speedup 1.0000x reference)
//
#include <hip/hip_runtime.h>
#include <hip/hip_fp16.h>

// Problem constants
#define NB 4      // batch
#define CI 256    // input channels
#define HH 64
#define WW 64
#define MC 64     // compressed channels
#define HS 128    // H*2
#define WS_ 128   // W*2
#define HW 4096   // HH*WW

typedef __attribute__((ext_vector_type(8))) short short8v;   // 8 bf16 (4 VGPRs)
typedef __attribute__((ext_vector_type(4))) float floatx4;   // MFMA C/D

__device__ inline unsigned short f2bf(float f) {
  union { float f; unsigned u; } v; v.f = f;
  unsigned r = v.u + 0x7FFFu + ((v.u >> 16) & 1u);   // RNE
  return (unsigned short)(r >> 16);
}

// ---------------------------------------------------------------------------
// Prep: rearrange weights into MFMA A-fragment layout (bf16).  (unchanged)
// ---------------------------------------------------------------------------
__global__ __launch_bounds__(256) void prep_kernel(
    const float* __restrict__ w_comp, const float* __restrict__ w_enc,
    unsigned short* __restrict__ Aw1, unsigned short* __restrict__ Aw2) {
  int i = blockIdx.x * 256 + threadIdx.x;
  if (i < 16384) {                       // 8*64*32
    int kl = i & 31, o = (i >> 5) & 63, ks = i >> 11;
    Aw1[i] = f2bf(w_comp[o * 256 + ks * 32 + kl]);
  } else if (i < 16384 + 64512) {        // 18*112*32
    int j = i - 16384;
    int kl = j & 31, o = (j >> 5) % 112, ks = (j >> 5) / 112;
    int t = ks >> 1, m = (ks & 1) * 32 + kl;
    Aw2[j] = (o < 100) ? f2bf(w_enc[o * 576 + m * 9 + t]) : (unsigned short)0;
  }
}

// ---------------------------------------------------------------------------
// Kernel 1: 1x1 conv via MFMA, K-split 4 (unchanged, round-10 version).
// ---------------------------------------------------------------------------
__global__ __launch_bounds__(512, 1) void conv1x1_mfma(
    const float* __restrict__ x, const unsigned short* __restrict__ Aw1,
    const float* __restrict__ b_comp, unsigned short* __restrict__ comp_cl) {
  __shared__ float pacc[2][64][49];
  int tid = threadIdx.x;
  int wid = tid >> 6, lane = tid & 63;
  int tileid = wid & 1, kh = wid >> 1;    // kh 0..3
  int Nt = blockIdx.x * 2 + tileid;       // 0..1023
  int n = Nt >> 8, pixbase = (Nt & 255) * 16;
  int l15 = lane & 15, g = lane >> 4;
  int pix = pixbase + l15;

  floatx4 acc[4];
#pragma unroll
  for (int ot = 0; ot < 4; ++ot) acc[ot] = (floatx4){0.f, 0.f, 0.f, 0.f};

  const float* xb = x + (size_t)n * CI * HW + pix;
  const unsigned short* ab = Aw1 + l15 * 32 + g * 8;

#pragma unroll
  for (int s = 0; s < 2; ++s) {
    int ks = kh * 2 + s;
    int c0 = ks * 32 + g * 8;
    short8v bfrag;
#pragma unroll
    for (int j = 0; j < 8; ++j)
      bfrag[j] = (short)f2bf(xb[(size_t)(c0 + j) * HW]);
#pragma unroll
    for (int ot = 0; ot < 4; ++ot) {
      short8v af = *(const short8v*)(ab + (ks * 64 + ot * 16) * 32);
      acc[ot] = __builtin_amdgcn_mfma_f32_16x16x32_bf16(af, bfrag, acc[ot], 0, 0, 0);
    }
  }

  if (kh > 0) {
#pragma unroll
    for (int ot = 0; ot < 4; ++ot)
#pragma unroll
      for (int r = 0; r < 4; ++r)
        pacc[tileid][lane][(kh - 1) * 16 + ot * 4 + r] = acc[ot][r];
  }
  __syncthreads();
  if (kh == 0) {
    unsigned short* cp = comp_cl + ((size_t)(n * HW + pix)) * 64;
#pragma unroll
    for (int ot = 0; ot < 4; ++ot) {
      const float4 bv = *(const float4*)(b_comp + ot * 16 + g * 4);
      float v0 = acc[ot][0] + bv.x, v1 = acc[ot][1] + bv.y;
      float v2 = acc[ot][2] + bv.z, v3 = acc[ot][3] + bv.w;
#pragma unroll
      for (int sl = 0; sl < 3; ++sl) {
        v0 += pacc[tileid][lane][sl * 16 + ot * 4 + 0];
        v1 += pacc[tileid][lane][sl * 16 + ot * 4 + 1];
        v2 += pacc[tileid][lane][sl * 16 + ot * 4 + 2];
        v3 += pacc[tileid][lane][sl * 16 + ot * 4 + 3];
      }
      unsigned h01 = (unsigned)f2bf(v0) | ((unsigned)f2bf(v1) << 16);
      unsigned h23 = (unsigned)f2bf(v2) | ((unsigned)f2bf(v3) << 16);
      *(int2*)(cp + ot * 16 + g * 4) = make_int2((int)h01, (int)h23);
    }
  }
}

// ---------------------------------------------------------------------------
// Kernel 2 (FUSED, v3): 256-thr blocks, tile = 4x16 outputs (2x8 input core).
// __launch_bounds__(256,2) -> 256-reg budget: all ~100 live values in ARCH
// VGPRs (no accvgpr round-trips; the r5-r13 plateau's hidden tax).
// Grid 1024 -> 4 blocks/CU = 16 waves/CU (iso-occupancy with r13).
// Phase 1: kenc K-split-4 across 4 waves (one wave = all 16 core px).
// Phase 2: r13's horizontal-pair mapping, 4 stages x 64 ch.
// LDS 25.3 KB (pacc 21.8K union xp 18.4K, + wlds 3.6K).
// ---------------------------------------------------------------------------
#define TAPP(W, V, fa, fb)                                                     \
  asm("v_fma_mix_f32 %0, %1, %2, %0 op_sel:[0,0,0] op_sel_hi:[1,0,0]"          \
      : "+v"(a00) : "v"(W), "v"(fa));                                          \
  asm("v_fma_mix_f32 %0, %1, %2, %0 op_sel:[1,0,0] op_sel_hi:[1,0,0]"          \
      : "+v"(a01) : "v"(W), "v"(fa));                                          \
  asm("v_fma_mix_f32 %0, %1, %2, %0 op_sel:[0,0,0] op_sel_hi:[1,0,0]"          \
      : "+v"(a10) : "v"(V), "v"(fb));                                          \
  asm("v_fma_mix_f32 %0, %1, %2, %0 op_sel:[1,0,0] op_sel_hi:[1,0,0]"          \
      : "+v"(a11) : "v"(V), "v"(fb));

#define ROWP(WA, WB, WC, WD, WE, VA, VB, VC, VD, VE, RP)                       \
  { const float* rr = (RP);                                                    \
    float2 f01 = *(const float2*)(rr);                                         \
    float2 f23 = *(const float2*)(rr + 2);                                     \
    float2 f45 = *(const float2*)(rr + 4);                                     \
    TAPP(WA, VA, f01.x, f01.y) TAPP(WB, VB, f01.y, f23.x)                      \
    TAPP(WC, VC, f23.x, f23.y) TAPP(WD, VD, f23.y, f45.x)                      \
    TAPP(WE, VE, f45.x, f45.y) }

__device__ __forceinline__ float4 load_slot18(const float* __restrict__ xb,
                                              int h0, int w0, int f,
                                              bool interior) {
  int c = f / 18, rem = f - c * 18, r = rem / 3, h = rem - r * 3;
  int gh = h0 - 2 + r, gw = w0 - 2 + h * 4;
  if (interior) {
    const float* gp = xb + (size_t)c * HW + gh * WW + gw;
    float2 lo = *(const float2*)gp;       // gw even -> 8B aligned
    float2 hi = *(const float2*)(gp + 2);
    return make_float4(lo.x, lo.y, hi.x, hi.y);
  }
  int ghc = min(max(gh, 0), 63);
  const float* rowp = xb + (size_t)c * HW + ghc * WW;
  float v0 = rowp[min(max(gw + 0, 0), 63)];
  float v1 = rowp[min(max(gw + 1, 0), 63)];
  float v2 = rowp[min(max(gw + 2, 0), 63)];
  float v3 = rowp[min(max(gw + 3, 0), 63)];
  bool rok = ((unsigned)gh < 64u);
  v0 = (rok && (unsigned)(gw + 0) < 64u) ? v0 : 0.f;
  v1 = (rok && (unsigned)(gw + 1) < 64u) ? v1 : 0.f;
  v2 = (rok && (unsigned)(gw + 2) < 64u) ? v2 : 0.f;
  v3 = (rok && (unsigned)(gw + 3) < 64u) ? v3 : 0.f;
  return make_float4(v0, v1, v2, v3);
}

__global__ __launch_bounds__(256, 2) void fused_kernel(
    const float* __restrict__ x,
    const unsigned short* __restrict__ comp_cl,
    const unsigned short* __restrict__ Aw2,
    const float* __restrict__ b_enc,
    float* __restrict__ out) {
  __shared__ float smem[6336];                  // 25,344 B
  float* paccF = smem;                          // phase 1: [64][85]
  float* xp = smem;                             // phase 2: [64][72]
  unsigned int* wlds = (unsigned int*)(smem + 5440);    // [2][16][28]

  int tid = threadIdx.x;
  int bid = blockIdx.x;                 // tile(256) | n(4)
  int tile = bid & 255, n = bid >> 8;
  int tyi = tile >> 3, txi = tile & 7;  // 32 x 8 tiles of 4x16 outputs
  int ty0 = tyi * 4, tx0 = txi * 16;
  int h0 = tyi * 2, w0 = txi * 8;       // input core base (2 rows x 8 cols)

  int kh = tid >> 6, lane = tid & 63;   // wave = K-quarter
  int l15 = lane & 15, g = lane >> 4;   // l15 = core px index (py*8+px)

  // ================= phase 1: kenc for the 2x8 core px =====================
  {
    int pix = (h0 + (l15 >> 3)) * 64 + w0 + (l15 & 7);
    int y = pix >> 6, xcol = pix & 63;

    bool vm[9];
    int sh9[9];
#pragma unroll
    for (int t = 0; t < 9; ++t) {
      int dy = t / 3, dx = t % 3;
      vm[t] = ((unsigned)(y + dy - 1) < 64u) && ((unsigned)(xcol + dx - 1) < 64u);
      sh9[t] = (dy - 1) * 64 + (dx - 1);
    }

    floatx4 acc[7];
#pragma unroll
    for (int ot = 0; ot < 7; ++ot) acc[ot] = (floatx4){0.f, 0.f, 0.f, 0.f};

    const unsigned short* cb = comp_cl + (size_t)n * HW * 64;
    const unsigned short* ab = Aw2 + l15 * 32 + g * 8;
    const short8v zv = {0, 0, 0, 0, 0, 0, 0, 0};

    int ks0 = (kh < 2) ? kh * 5 : 10 + (kh - 2) * 4;
    int len = (kh < 2) ? 5 : 4;
#pragma unroll
    for (int s = 0; s < 5; ++s) {
      if (s < len) {
        int ks = ks0 + s;
        int t = ks >> 1, mh = ks & 1;
        const unsigned short* bp = cb + (pix + sh9[t]) * 64 + mh * 32 + g * 8;
        short8v bfrag = vm[t] ? *(const short8v*)bp : zv;
#pragma unroll
        for (int ot = 0; ot < 7; ++ot) {
          short8v af = *(const short8v*)(ab + (ks * 112 + ot * 16) * 32);
          acc[ot] = __builtin_amdgcn_mfma_f32_16x16x32_bf16(af, bfrag, acc[ot], 0, 0, 0);
        }
      }
    }

    if (kh > 0) {
#pragma unroll
      for (int ot = 0; ot < 7; ++ot)
#pragma unroll
        for (int r = 0; r < 4; ++r)
          paccF[lane * 85 + (kh - 1) * 28 + ot * 4 + r] = acc[ot][r];
    }
    __syncthreads();
    if (kh == 0) {
#pragma unroll
      for (int ot = 0; ot < 7; ++ot) {
        int ob = ot * 16 + g * 4; if (ob > 96) ob = 96;
        const float4 bv = *(const float4*)(b_enc + ob);
        acc[ot][0] += bv.x; acc[ot][1] += bv.y;
        acc[ot][2] += bv.z; acc[ot][3] += bv.w;
#pragma unroll
        for (int sl = 0; sl < 3; ++sl) {
          acc[ot][0] += paccF[lane * 85 + sl * 28 + ot * 4 + 0];
          acc[ot][1] += paccF[lane * 85 + sl * 28 + ot * 4 + 1];
          acc[ot][2] += paccF[lane * 85 + sl * 28 + ot * 4 + 2];
          acc[ot][3] += paccF[lane * 85 + sl * 28 + ot * 4 + 3];
        }
      }

      // per-r softmax; normalized values back into acc[ot][r]
#pragma unroll
      for (int r = 0; r < 4; ++r) {
        float m = acc[0][r];
#pragma unroll
        for (int ot = 1; ot < 6; ++ot) m = fmaxf(m, acc[ot][r]);
        if (g == 0) m = fmaxf(m, acc[6][r]);
        m = fmaxf(m, __shfl_xor(m, 16));
        m = fmaxf(m, __shfl_xor(m, 32));
        float s = 0.f;
        float e[7];
#pragma unroll
        for (int ot = 0; ot < 7; ++ot) {
          bool val = (ot < 6) || (g == 0);
          e[ot] = val ? __expf(acc[ot][r] - m) : 0.f;
          s += e[ot];
        }
        s += __shfl_xor(s, 16);
        s += __shfl_xor(s, 32);
        float inv = 1.f / s;
#pragma unroll
        for (int ot = 0; ot < 7; ++ot) acc[ot][r] = e[ot] * inv;
      }

      // pack f16 pairs into LDS: wlds[sh][px=l15][k=ot*4+g]
#pragma unroll
      for (int sh = 0; sh < 2; ++sh) {
        unsigned int* wq = wlds + sh * 448 + l15 * 28;
#pragma unroll
        for (int ot = 0; ot < 7; ++ot) {
          if ((ot < 6) || (g == 0)) {
            __half2 h2 = __floats2half2_rn(acc[ot][2 * sh], acc[ot][2 * sh + 1]);
            wq[ot * 4 + g] = *reinterpret_cast<unsigned int*>(&h2);
          }
        }
      }
    }
  }
  __syncthreads();   // wlds complete; paccF dead

  // ================= phase 2: reassembly, horizontal-pair mapping ==========
  int cslot = tid >> 4;                 // 0..15
  int rem = tid & 15;
  int py = rem >> 3;                    // input row 0..1
  int shsel = (rem >> 2) & 1;           // output sub-row
  int pxp = rem & 3;                    // input col pair 0..3
  int oy = ty0 + 2 * py + shsel;
  int ox0 = tx0 + 4 * pxp;
  int cb0 = 2 * pxp;                    // halo col base (even -> b64 aligned)

  // weights: 2 adjacent px, ONE sh plane = 50 packed dwords (named uint4s)
  const unsigned int* wtA = wlds + shsel * 448 + (py * 8 + 2 * pxp) * 28;
  const unsigned int* wtB = wtA + 28;
  uint4 A0 = *(const uint4*)(wtA + 0);
  uint4 A1 = *(const uint4*)(wtA + 4);
  uint4 A2 = *(const uint4*)(wtA + 8);
  uint4 A3 = *(const uint4*)(wtA + 12);
  uint4 A4 = *(const uint4*)(wtA + 16);
  uint4 A5 = *(const uint4*)(wtA + 20);
  unsigned int A6 = wtA[24];
  uint4 B0 = *(const uint4*)(wtB + 0);
  uint4 B1 = *(const uint4*)(wtB + 4);
  uint4 B2 = *(const uint4*)(wtB + 8);
  uint4 B3 = *(const uint4*)(wtB + 12);
  uint4 B4 = *(const uint4*)(wtB + 16);
  uint4 B5 = *(const uint4*)(wtB + 20);
  unsigned int B6 = wtB[24];

  bool interior = (tyi >= 1) && (tyi <= 30) && (txi >= 1) && (txi <= 6);
  bool halfv = tid < 128;

  for (int cs = 0; cs < 4; ++cs) {
    const float* xb = x + (size_t)(n * CI + cs * 64) * HW;
    // stage 64 ch x 6x12 halo: 1152 f4 slots, 4.5 per thread
    float4 s0 = load_slot18(xb, h0, w0, tid,        interior);
    float4 s1 = load_slot18(xb, h0, w0, tid + 256,  interior);
    float4 s2 = load_slot18(xb, h0, w0, tid + 512,  interior);
    float4 s3 = load_slot18(xb, h0, w0, tid + 768,  interior);
    float4 s4 = halfv ? load_slot18(xb, h0, w0, tid + 1024, interior)
                      : make_float4(0.f, 0.f, 0.f, 0.f);
    if (cs > 0) __syncthreads();        // prior compute done before overwrite
    *(float4*)(xp + 4 * (tid))        = s0;
    *(float4*)(xp + 4 * (tid + 256))  = s1;
    *(float4*)(xp + 4 * (tid + 512))  = s2;
    *(float4*)(xp + 4 * (tid + 768))  = s3;
    if (halfv) *(float4*)(xp + 4 * (tid + 1024)) = s4;
    __syncthreads();

    float* outb = out + ((size_t)(n * CI + cs * 64) * HS + oy) * WS_ + ox0;
#pragma unroll
    for (int it = 0; it < 4; ++it) {
      int cl = it * 16 + cslot;
      const float* p = xp + cl * 72 + py * 12 + cb0;
      float a00 = 0.f, a01 = 0.f, a10 = 0.f, a11 = 0.f;
      ROWP(A0.x, A0.y, A0.z, A0.w, A1.x, B0.x, B0.y, B0.z, B0.w, B1.x, p)
      ROWP(A1.y, A1.z, A1.w, A2.x, A2.y, B1.y, B1.z, B1.w, B2.x, B2.y, p + 12)
      ROWP(A2.z, A2.w, A3.x, A3.y, A3.z, B2.z, B2.w, B3.x, B3.y, B3.z, p + 24)
      ROWP(A3.w, A4.x, A4.y, A4.z, A4.w, B3.w, B4.x, B4.y, B4.z, B4.w, p + 36)
      ROWP(A5.x, A5.y, A5.z, A5.w, A6,   B5.x, B5.y, B5.z, B5.w, B6,   p + 48)
      *(float4*)(outb + (size_t)cl * HS * WS_) = make_float4(a00, a01, a10, a11);
    }
  }
}

// ---------------------------------------------------------------------------
extern "C" void kernel_launch(void* const* d_in, const int* in_sizes, int n_in,
                              void* d_out, int out_size, void* d_ws,
                              size_t ws_size, hipStream_t stream) {
  const float* x      = (const float*)d_in[0];
  const float* w_comp = (const float*)d_in[1];
  const float* b_comp = (const float*)d_in[2];
  const float* w_enc  = (const float*)d_in[3];
  const float* b_enc  = (const float*)d_in[4];
  float* out = (float*)d_out;

  char* ws = (char*)d_ws;
  unsigned short* comp_cl = (unsigned short*)ws;                  // 2,097,152 B
  unsigned short* Aw1     = (unsigned short*)(ws + 2097152);      //    32,768 B
  unsigned short* Aw2     = (unsigned short*)(ws + 2129920);      //   129,024 B

  prep_kernel<<<dim3(316), 256, 0, stream>>>(w_comp, w_enc, Aw1, Aw2);
  conv1x1_mfma<<<dim3(512), 512, 0, stream>>>(x, Aw1, b_comp, comp_cl);
  fused_kernel<<<dim3(1024), 256, 0, stream>>>(x, comp_cl, Aw2, b_enc, out);
}

// Round 15
// 55.337 us; speedup vs baseline: 1.2356x; 1.2356x over previous
//
#include <hip/hip_runtime.h>
#include <hip/hip_fp16.h>

// Problem constants
#define NB 4      // batch
#define CI 256    // input channels
#define HH 64
#define WW 64
#define MC 64     // compressed channels
#define HS 128    // H*2
#define WS_ 128   // W*2
#define HW 4096   // HH*WW

typedef __attribute__((ext_vector_type(8))) short short8v;   // 8 bf16 (4 VGPRs)
typedef __attribute__((ext_vector_type(4))) float floatx4;   // MFMA C/D

__device__ inline unsigned short f2bf(float f) {
  union { float f; unsigned u; } v; v.f = f;
  unsigned r = v.u + 0x7FFFu + ((v.u >> 16) & 1u);   // RNE
  return (unsigned short)(r >> 16);
}

// ---------------------------------------------------------------------------
// Prep: rearrange weights into MFMA A-fragment layout (bf16).  (unchanged)
// ---------------------------------------------------------------------------
__global__ __launch_bounds__(256) void prep_kernel(
    const float* __restrict__ w_comp, const float* __restrict__ w_enc,
    unsigned short* __restrict__ Aw1, unsigned short* __restrict__ Aw2) {
  int i = blockIdx.x * 256 + threadIdx.x;
  if (i < 16384) {                       // 8*64*32
    int kl = i & 31, o = (i >> 5) & 63, ks = i >> 11;
    Aw1[i] = f2bf(w_comp[o * 256 + ks * 32 + kl]);
  } else if (i < 16384 + 64512) {        // 18*112*32
    int j = i - 16384;
    int kl = j & 31, o = (j >> 5) % 112, ks = (j >> 5) / 112;
    int t = ks >> 1, m = (ks & 1) * 32 + kl;
    Aw2[j] = (o < 100) ? f2bf(w_enc[o * 576 + m * 9 + t]) : (unsigned short)0;
  }
}

// ---------------------------------------------------------------------------
// Kernel 1: 1x1 conv via MFMA, K-split 4 (unchanged, round-10 version).
// ---------------------------------------------------------------------------
__global__ __launch_bounds__(512, 1) void conv1x1_mfma(
    const float* __restrict__ x, const unsigned short* __restrict__ Aw1,
    const float* __restrict__ b_comp, unsigned short* __restrict__ comp_cl) {
  __shared__ float pacc[2][64][49];
  int tid = threadIdx.x;
  int wid = tid >> 6, lane = tid & 63;
  int tileid = wid & 1, kh = wid >> 1;    // kh 0..3
  int Nt = blockIdx.x * 2 + tileid;       // 0..1023
  int n = Nt >> 8, pixbase = (Nt & 255) * 16;
  int l15 = lane & 15, g = lane >> 4;
  int pix = pixbase + l15;

  floatx4 acc[4];
#pragma unroll
  for (int ot = 0; ot < 4; ++ot) acc[ot] = (floatx4){0.f, 0.f, 0.f, 0.f};

  const float* xb = x + (size_t)n * CI * HW + pix;
  const unsigned short* ab = Aw1 + l15 * 32 + g * 8;

#pragma unroll
  for (int s = 0; s < 2; ++s) {
    int ks = kh * 2 + s;
    int c0 = ks * 32 + g * 8;
    short8v bfrag;
#pragma unroll
    for (int j = 0; j < 8; ++j)
      bfrag[j] = (short)f2bf(xb[(size_t)(c0 + j) * HW]);
#pragma unroll
    for (int ot = 0; ot < 4; ++ot) {
      short8v af = *(const short8v*)(ab + (ks * 64 + ot * 16) * 32);
      acc[ot] = __builtin_amdgcn_mfma_f32_16x16x32_bf16(af, bfrag, acc[ot], 0, 0, 0);
    }
  }

  if (kh > 0) {
#pragma unroll
    for (int ot = 0; ot < 4; ++ot)
#pragma unroll
      for (int r = 0; r < 4; ++r)
        pacc[tileid][lane][(kh - 1) * 16 + ot * 4 + r] = acc[ot][r];
  }
  __syncthreads();
  if (kh == 0) {
    unsigned short* cp = comp_cl + ((size_t)(n * HW + pix)) * 64;
#pragma unroll
    for (int ot = 0; ot < 4; ++ot) {
      const float4 bv = *(const float4*)(b_comp + ot * 16 + g * 4);
      float v0 = acc[ot][0] + bv.x, v1 = acc[ot][1] + bv.y;
      float v2 = acc[ot][2] + bv.z, v3 = acc[ot][3] + bv.w;
#pragma unroll
      for (int sl = 0; sl < 3; ++sl) {
        v0 += pacc[tileid][lane][sl * 16 + ot * 4 + 0];
        v1 += pacc[tileid][lane][sl * 16 + ot * 4 + 1];
        v2 += pacc[tileid][lane][sl * 16 + ot * 4 + 2];
        v3 += pacc[tileid][lane][sl * 16 + ot * 4 + 3];
      }
      unsigned h01 = (unsigned)f2bf(v0) | ((unsigned)f2bf(v1) << 16);
      unsigned h23 = (unsigned)f2bf(v2) | ((unsigned)f2bf(v3) << 16);
      *(int2*)(cp + ot * 16 + g * 4) = make_int2((int)h01, (int)h23);
    }
  }
}

// ---------------------------------------------------------------------------
// Kernel 2 (FUSED, r12 base + pipelined phase 2):
// Phase 1: kenc K-split-4 (2 row-waves x 4 kh), softmax -> packed-f16
//          weights in wlds.  (verbatim r12)
// Phase 2: 8 stages x 32 channels, DOUBLE-BUFFERED xp (2 x 15.4 KB union
//          dead paccF; smem total unchanged 50,688 B).  Per stage: issue
//          next-stage global loads -> compute current -> write next ->
//          ONE barrier.  HBM latency hides under ~200 fma_mix.
// ---------------------------------------------------------------------------
#define TAPP(W, V, fa, fb)                                                     \
  asm("v_fma_mix_f32 %0, %1, %2, %0 op_sel:[0,0,0] op_sel_hi:[1,0,0]"          \
      : "+v"(a00) : "v"(W), "v"(fa));                                          \
  asm("v_fma_mix_f32 %0, %1, %2, %0 op_sel:[1,0,0] op_sel_hi:[1,0,0]"          \
      : "+v"(a01) : "v"(W), "v"(fa));                                          \
  asm("v_fma_mix_f32 %0, %1, %2, %0 op_sel:[0,0,0] op_sel_hi:[1,0,0]"          \
      : "+v"(a10) : "v"(V), "v"(fb));                                          \
  asm("v_fma_mix_f32 %0, %1, %2, %0 op_sel:[1,0,0] op_sel_hi:[1,0,0]"          \
      : "+v"(a11) : "v"(V), "v"(fb));

#define ROWP(WA, WB, WC, WD, WE, VA, VB, VC, VD, VE, RP)                       \
  { const float* rr = (RP);                                                    \
    float2 f01 = *(const float2*)(rr);                                         \
    float2 f23 = *(const float2*)(rr + 2);                                     \
    float2 f45 = *(const float2*)(rr + 4);                                     \
    TAPP(WA, VA, f01.x, f01.y) TAPP(WB, VB, f01.y, f23.x)                      \
    TAPP(WC, VC, f23.x, f23.y) TAPP(WD, VD, f23.y, f45.x)                      \
    TAPP(WE, VE, f45.x, f45.y) }

// slot f in [0,960): c = f/30 (32 ch), r = (f%30)/5, h = f%5 (4-wide cols)
__device__ __forceinline__ float4 load_slot20(const float* __restrict__ xb,
                                              int h0, int w0, int f,
                                              bool interior) {
  int c = f / 30, rem = f - c * 30, r = rem / 5, h = rem - r * 5;
  int gh = h0 - 2 + r, gw = w0 - 2 + h * 4;
  if (interior) {
    const float* gp = xb + (size_t)c * HW + gh * WW + gw;
    float2 lo = *(const float2*)gp;       // gw even -> 8B aligned
    float2 hi = *(const float2*)(gp + 2);
    return make_float4(lo.x, lo.y, hi.x, hi.y);
  }
  int ghc = min(max(gh, 0), 63);
  const float* rowp = xb + (size_t)c * HW + ghc * WW;
  float v0 = rowp[min(max(gw + 0, 0), 63)];
  float v1 = rowp[min(max(gw + 1, 0), 63)];
  float v2 = rowp[min(max(gw + 2, 0), 63)];
  float v3 = rowp[min(max(gw + 3, 0), 63)];
  bool rok = ((unsigned)gh < 64u);
  v0 = (rok && (unsigned)(gw + 0) < 64u) ? v0 : 0.f;
  v1 = (rok && (unsigned)(gw + 1) < 64u) ? v1 : 0.f;
  v2 = (rok && (unsigned)(gw + 2) < 64u) ? v2 : 0.f;
  v3 = (rok && (unsigned)(gw + 3) < 64u) ? v3 : 0.f;
  return make_float4(v0, v1, v2, v3);
}

__global__ __launch_bounds__(512, 4) void fused_kernel(
    const float* __restrict__ x,
    const unsigned short* __restrict__ comp_cl,
    const unsigned short* __restrict__ Aw2,
    const float* __restrict__ b_enc,
    float* __restrict__ out) {
  __shared__ float smem[12672];                 // 50,688 B (same as r12)
  float* paccF = smem;                          // phase 1: [2][64][85]
  // phase 2: two 32-ch buffers [32][120] = 3840 floats each (union paccF)
  unsigned int* wlds = (unsigned int*)(smem + 10880);   // [2][2][16][28]

  int tid = threadIdx.x;
  int bid = blockIdx.x;                 // tile(128) | n(4)
  int tile = bid & 127, n = bid >> 7;
  int tyi = tile >> 2, txi = tile & 3;  // 32 x 4 tiles of 4x32 outputs
  int ty0 = tyi * 4, tx0 = txi * 32;
  int h0 = tyi * 2, w0 = txi * 16;      // input core base (2 rows x 16 cols)

  int wid = tid >> 6, lane = tid & 63;
  int tileid = wid & 1, kh = wid >> 1;  // row-wave, K-quarter
  int l15 = lane & 15, g = lane >> 4;

  // ================= phase 1: kenc for the 2x16 core px ====================
  {
    int pix = (h0 + tileid) * 64 + w0 + l15;
    int y = pix >> 6, xcol = pix & 63;

    bool vm[9];
    int sh9[9];
#pragma unroll
    for (int t = 0; t < 9; ++t) {
      int dy = t / 3, dx = t % 3;
      vm[t] = ((unsigned)(y + dy - 1) < 64u) && ((unsigned)(xcol + dx - 1) < 64u);
      sh9[t] = (dy - 1) * 64 + (dx - 1);
    }

    floatx4 acc[7];
#pragma unroll
    for (int ot = 0; ot < 7; ++ot) acc[ot] = (floatx4){0.f, 0.f, 0.f, 0.f};

    const unsigned short* cb = comp_cl + (size_t)n * HW * 64;
    const unsigned short* ab = Aw2 + l15 * 32 + g * 8;
    const short8v zv = {0, 0, 0, 0, 0, 0, 0, 0};

    int ks0 = (kh < 2) ? kh * 5 : 10 + (kh - 2) * 4;
    int len = (kh < 2) ? 5 : 4;
#pragma unroll
    for (int s = 0; s < 5; ++s) {
      if (s < len) {
        int ks = ks0 + s;
        int t = ks >> 1, mh = ks & 1;
        const unsigned short* bp = cb + (pix + sh9[t]) * 64 + mh * 32 + g * 8;
        short8v bfrag = vm[t] ? *(const short8v*)bp : zv;
#pragma unroll
        for (int ot = 0; ot < 7; ++ot) {
          short8v af = *(const short8v*)(ab + (ks * 112 + ot * 16) * 32);
          acc[ot] = __builtin_amdgcn_mfma_f32_16x16x32_bf16(af, bfrag, acc[ot], 0, 0, 0);
        }
      }
    }

    if (kh > 0) {
#pragma unroll
      for (int ot = 0; ot < 7; ++ot)
#pragma unroll
        for (int r = 0; r < 4; ++r)
          paccF[(tileid * 64 + lane) * 85 + (kh - 1) * 28 + ot * 4 + r] =
              acc[ot][r];
    }
    __syncthreads();
    if (kh == 0) {
#pragma unroll
      for (int ot = 0; ot < 7; ++ot) {
        int ob = ot * 16 + g * 4; if (ob > 96) ob = 96;
        const float4 bv = *(const float4*)(b_enc + ob);
        acc[ot][0] += bv.x; acc[ot][1] += bv.y;
        acc[ot][2] += bv.z; acc[ot][3] += bv.w;
#pragma unroll
        for (int sl = 0; sl < 3; ++sl) {
          acc[ot][0] += paccF[(tileid * 64 + lane) * 85 + sl * 28 + ot * 4 + 0];
          acc[ot][1] += paccF[(tileid * 64 + lane) * 85 + sl * 28 + ot * 4 + 1];
          acc[ot][2] += paccF[(tileid * 64 + lane) * 85 + sl * 28 + ot * 4 + 2];
          acc[ot][3] += paccF[(tileid * 64 + lane) * 85 + sl * 28 + ot * 4 + 3];
        }
      }

      // per-r softmax; normalized values back into acc[ot][r]
#pragma unroll
      for (int r = 0; r < 4; ++r) {
        float m = acc[0][r];
#pragma unroll
        for (int ot = 1; ot < 6; ++ot) m = fmaxf(m, acc[ot][r]);
        if (g == 0) m = fmaxf(m, acc[6][r]);
        m = fmaxf(m, __shfl_xor(m, 16));
        m = fmaxf(m, __shfl_xor(m, 32));
        float s = 0.f;
        float e[7];
#pragma unroll
        for (int ot = 0; ot < 7; ++ot) {
          bool val = (ot < 6) || (g == 0);
          e[ot] = val ? __expf(acc[ot][r] - m) : 0.f;
          s += e[ot];
        }
        s += __shfl_xor(s, 16);
        s += __shfl_xor(s, 32);
        float inv = 1.f / s;
#pragma unroll
        for (int ot = 0; ot < 7; ++ot) acc[ot][r] = e[ot] * inv;
      }

      // pack f16 pairs into LDS: wlds[sh][row=tileid][px=l15][k=ot*4+g]
#pragma unroll
      for (int sh = 0; sh < 2; ++sh) {
        unsigned int* wq = wlds + sh * 896 + tileid * 448 + l15 * 28;
#pragma unroll
        for (int ot = 0; ot < 7; ++ot) {
          if ((ot < 6) || (g == 0)) {
            __half2 h2 = __floats2half2_rn(acc[ot][2 * sh], acc[ot][2 * sh + 1]);
            wq[ot * 4 + g] = *reinterpret_cast<unsigned int*>(&h2);
          }
        }
      }
    }
  }
  __syncthreads();   // wlds complete; paccF dead

  // ================= phase 2: pipelined reassembly, 8 x 32-ch stages =======
  int cslot = tid >> 5;                 // 0..15
  int rem = tid & 31;
  int py = rem >> 4;                    // input row 0..1
  int shsel = (rem >> 3) & 1;           // output sub-row
  int pxp = rem & 7;                    // input col pair 0..7
  int oy = ty0 + 2 * py + shsel;
  int ox0 = tx0 + 4 * pxp;
  int cb0 = 2 * pxp;                    // halo col base (even -> b64 aligned)

  // weights: 2 adjacent px, ONE sh plane = 50 packed dwords (named uint4s)
  const unsigned int* wtA = wlds + shsel * 896 + py * 448 + cb0 * 28;
  const unsigned int* wtB = wtA + 28;
  uint4 A0 = *(const uint4*)(wtA + 0);
  uint4 A1 = *(const uint4*)(wtA + 4);
  uint4 A2 = *(const uint4*)(wtA + 8);
  uint4 A3 = *(const uint4*)(wtA + 12);
  uint4 A4 = *(const uint4*)(wtA + 16);
  uint4 A5 = *(const uint4*)(wtA + 20);
  unsigned int A6 = wtA[24];
  uint4 B0 = *(const uint4*)(wtB + 0);
  uint4 B1 = *(const uint4*)(wtB + 4);
  uint4 B2 = *(const uint4*)(wtB + 8);
  uint4 B3 = *(const uint4*)(wtB + 12);
  uint4 B4 = *(const uint4*)(wtB + 16);
  uint4 B5 = *(const uint4*)(wtB + 20);
  unsigned int B6 = wtB[24];

  bool interior = (tyi >= 1) && (tyi <= 30) && (txi >= 1) && (txi <= 2);
  bool extra = tid < 448;               // 960 = 512 + 448 slots per stage

  // prologue: stage 0 (channels 0..31)
  {
    const float* xb = x + (size_t)(n * CI) * HW;
    float4 s0 = load_slot20(xb, h0, w0, tid, interior);
    float4 s1 = extra ? load_slot20(xb, h0, w0, tid + 512, interior)
                      : make_float4(0.f, 0.f, 0.f, 0.f);
    float* xpb = smem;                  // buffer 0
    *(float4*)(xpb + 4 * tid) = s0;
    if (extra) *(float4*)(xpb + 4 * (tid + 512)) = s1;
  }
  __syncthreads();

  for (int cs = 0; cs < 8; ++cs) {
    float* xpcur = smem + (cs & 1) * 3840;
    float* xpnxt = smem + ((cs + 1) & 1) * 3840;

    // issue next-stage loads FIRST (hide HBM latency under compute)
    float4 t0 = make_float4(0.f, 0.f, 0.f, 0.f);
    float4 t1 = make_float4(0.f, 0.f, 0.f, 0.f);
    if (cs < 7) {
      const float* xbn = x + (size_t)(n * CI + (cs + 1) * 32) * HW;
      t0 = load_slot20(xbn, h0, w0, tid, interior);
      if (extra) t1 = load_slot20(xbn, h0, w0, tid + 512, interior);
    }

    // compute current stage: 2 channel-iters
    float* outb = out + ((size_t)(n * CI + cs * 32) * HS + oy) * WS_ + ox0;
#pragma unroll
    for (int it = 0; it < 2; ++it) {
      int cl = it * 16 + cslot;
      const float* p = xpcur + cl * 120 + py * 20 + cb0;
      float a00 = 0.f, a01 = 0.f, a10 = 0.f, a11 = 0.f;
      ROWP(A0.x, A0.y, A0.z, A0.w, A1.x, B0.x, B0.y, B0.z, B0.w, B1.x, p)
      ROWP(A1.y, A1.z, A1.w, A2.x, A2.y, B1.y, B1.z, B1.w, B2.x, B2.y, p + 20)
      ROWP(A2.z, A2.w, A3.x, A3.y, A3.z, B2.z, B2.w, B3.x, B3.y, B3.z, p + 40)
      ROWP(A3.w, A4.x, A4.y, A4.z, A4.w, B3.w, B4.x, B4.y, B4.z, B4.w, p + 60)
      ROWP(A5.x, A5.y, A5.z, A5.w, A6,   B5.x, B5.y, B5.z, B5.w, B6,   p + 80)
      *(float4*)(outb + (size_t)cl * HS * WS_) = make_float4(a00, a01, a10, a11);
    }

    // write next buffer + single barrier per stage
    if (cs < 7) {
      *(float4*)(xpnxt + 4 * tid) = t0;
      if (extra) *(float4*)(xpnxt + 4 * (tid + 512)) = t1;
      __syncthreads();
    }
  }
}

// ---------------------------------------------------------------------------
extern "C" void kernel_launch(void* const* d_in, const int* in_sizes, int n_in,
                              void* d_out, int out_size, void* d_ws,
                              size_t ws_size, hipStream_t stream) {
  const float* x      = (const float*)d_in[0];
  const float* w_comp = (const float*)d_in[1];
  const float* b_comp = (const float*)d_in[2];
  const float* w_enc  = (const float*)d_in[3];
  const float* b_enc  = (const float*)d_in[4];
  float* out = (float*)d_out;

  char* ws = (char*)d_ws;
  unsigned short* comp_cl = (unsigned short*)ws;                  // 2,097,152 B
  unsigned short* Aw1     = (unsigned short*)(ws + 2097152);      //    32,768 B
  unsigned short* Aw2     = (unsigned short*)(ws + 2129920);      //   129,024 B

  prep_kernel<<<dim3(316), 256, 0, stream>>>(w_comp, w_enc, Aw1, Aw2);
  conv1x1_mfma<<<dim3(512), 512, 0, stream>>>(x, Aw1, b_comp, comp_cl);
  fused_kernel<<<dim3(512), 512, 0, stream>>>(x, comp_cl, Aw2, b_enc, out);
}